// Round 6
// baseline (517.276 us; speedup 1.0000x reference)
//
#include <hip/hip_runtime.h>
#include <cstdint>
#include <cstddef>

#define DEVINL __device__ __forceinline__

typedef __attribute__((ext_vector_type(8))) short short8;
typedef __attribute__((ext_vector_type(4))) float f32x4;
typedef unsigned short u16;
typedef unsigned int u32;

// ---------- bf16 helpers (RNE) ----------
DEVINL u16 f2b(float f) {
    u32 u = __float_as_uint(f);
    u32 r = (u + 0x7fffu + ((u >> 16) & 1u)) >> 16;
    return (u16)r;
}
DEVINL float b2f(u16 h) { return __uint_as_float(((u32)h) << 16); }

DEVINL void gl_lds16(const void* g, void* l) {
    __builtin_amdgcn_global_load_lds(
        (const __attribute__((address_space(1))) void*)g,
        (__attribute__((address_space(3))) void*)l, 16, 0, 0);
}

// ---------- constants ----------
#define MROWS   25096
#define NTOK    3137
#define QE      25698304
#define LOG2E   1.4426950408889634f
#define SCL2    0.1803368801111204f   /* 0.125 * log2(e) */

// ---------- fp32 -> bf16 conversion ----------
__global__ __launch_bounds__(256) void cvt_kernel(const float* __restrict__ in,
                                                  u16* __restrict__ out, int n4) {
    int i = blockIdx.x * blockDim.x + threadIdx.x;
    int stride = gridDim.x * blockDim.x;
    for (int j = i; j < n4; j += stride) {
        float4 v = ((const float4*)in)[j];
        ushort4 o;
        o.x = f2b(v.x); o.y = f2b(v.y); o.z = f2b(v.z); o.w = f2b(v.w);
        ((ushort4*)out)[j] = o;
    }
}

// ================= 256x256 bf16 MFMA GEMM (round-4 structure, deeper prefetch) ===========
// A row-major [M][1024], B = [N][1024] (B^T input). K = 1024, NT = 16 K-tiles.
// 512 threads = 8 waves (2 M x 4 N). LDS: 2 bufs x (A[2][256][32] + B[2][256][32]).
// T2 swizzle: within each 64-B row (4 x 16-B slots), phys_slot = log_slot ^ ((row>>1)&3);
// LDS dest linear (gl_lds16), global SOURCE col pre-swizzled; frag reads same involution.
// NEW: all 8 of T+1's loads issued in p1+p2 -> waits vmcnt(8)@p2 (proves T k1, 4 phases old)
// and vmcnt(4)@p4 (proves T+1 k0, 3 phases old). Never drains mid-loop.

#define LDS_BUF 32768   // elems per buffer (A 16384 + B 16384)
#define NTILES  16

template <int MODE>
__global__ __launch_bounds__(512, 2) void gemm256(const u16* __restrict__ A,
                                                  const u16* __restrict__ B,
                                                  u16* __restrict__ q_out,
                                                  u16* __restrict__ k_out,
                                                  u16* __restrict__ v_out,
                                                  const float* __restrict__ bias,
                                                  float* __restrict__ f_out, int M) {
    __shared__ u16 lds[2 * LDS_BUF];   // 128 KiB
    const int tid = threadIdx.x, lane = tid & 63, w = tid >> 6;
    const int Mm1 = M - 1;

    // bijective XCD swizzle (m204)
    const u32 nwg = gridDim.x * gridDim.y;
    const u32 orig = blockIdx.y * gridDim.x + blockIdx.x;
    const u32 q8 = nwg >> 3, r8 = nwg & 7, xcd = orig & 7, rest = orig >> 3;
    const u32 wg = (xcd < r8 ? xcd * (q8 + 1) : r8 * (q8 + 1) + (xcd - r8) * q8) + rest;
    const int m0 = (int)(wg / gridDim.x) * 256;
    const int n0 = (int)(wg % gridDim.x) * 256;

    const int wm = w >> 2, wn = w & 3;

    const int stRow = lane >> 2;
    const int stCol = (((lane & 3) ^ ((lane >> 3) & 3)) << 3);

    const int slotOff = (((lane >> 4) ^ ((lane >> 1) & 3)) << 3);
    const int rdA = (wm * 128 + (lane & 15)) * 32 + slotOff;
    const int rdB = (wn * 64 + (lane & 15)) * 32 + slotOff + 16384;

#define STAGE_A(NB, KK, KT) do {                                              \
    _Pragma("unroll") for (int j_ = 0; j_ < 2; ++j_) {                        \
        const int c_ = (w << 1) | j_;                                         \
        int r_ = m0 + c_ * 16 + stRow; if (r_ > Mm1) r_ = Mm1;                \
        gl_lds16(A + (size_t)r_ * 1024 + (KT) + (KK) * 32 + stCol,            \
                 lds + (NB) + (KK) * 8192 + c_ * 512);                        \
    } } while (0)

#define STAGE_B(NB, KK, KT) do {                                              \
    _Pragma("unroll") for (int j_ = 0; j_ < 2; ++j_) {                        \
        const int c_ = (w << 1) | j_;                                         \
        const int r_ = n0 + c_ * 16 + stRow;                                  \
        gl_lds16(B + (size_t)r_ * 1024 + (KT) + (KK) * 32 + stCol,            \
                 lds + (NB) + 16384 + (KK) * 8192 + c_ * 512);                \
    } } while (0)

#define LDA4(CB, KK, MB) do {                                                 \
    _Pragma("unroll") for (int i_ = 0; i_ < 4; ++i_)                          \
        aF[i_] = *(const short8*)&lds[(CB) + (KK) * 8192 + rdA +              \
                                      ((MB) + i_) * 16 * 32];                 \
    } while (0)

#define LDB4(CB, KK) do {                                                     \
    _Pragma("unroll") for (int i_ = 0; i_ < 4; ++i_)                          \
        bF[i_] = *(const short8*)&lds[(CB) + (KK) * 8192 + rdB +              \
                                      i_ * 16 * 32];                          \
    } while (0)

#define MFMA16(MB) do {                                                       \
    _Pragma("unroll") for (int i_ = 0; i_ < 4; ++i_)                          \
        _Pragma("unroll") for (int n_ = 0; n_ < 4; ++n_)                      \
            acc[(MB) + i_][n_] = __builtin_amdgcn_mfma_f32_16x16x32_bf16(     \
                aF[i_], bF[n_], acc[(MB) + i_][n_], 0, 0, 0);                 \
    } while (0)

#define LGKM0_FENCE() do {                                                    \
    asm volatile("s_waitcnt lgkmcnt(0)" ::: "memory");                        \
    __builtin_amdgcn_sched_barrier(0); } while (0)

    f32x4 acc[8][4];
    const f32x4 zf = {0.f, 0.f, 0.f, 0.f};
#pragma unroll
    for (int i = 0; i < 8; ++i)
#pragma unroll
        for (int j = 0; j < 4; ++j) acc[i][j] = zf;

    // ---- prologue: stage tile 0 fully into buf0, prove k0 halves ----
    STAGE_A(0, 0, 0);
    STAGE_B(0, 0, 0);
    STAGE_A(0, 1, 0);
    STAGE_B(0, 1, 0);
    asm volatile("s_waitcnt vmcnt(4)" ::: "memory");
    __builtin_amdgcn_sched_barrier(0);
    __builtin_amdgcn_s_barrier();

    for (int T = 0; T < NTILES; ++T) {
        const int cb = (T & 1) * LDS_BUF;
        const int nb = ((T + 1) & 1) * LDS_BUF;
        const bool pf = (T < NTILES - 1);
        const int kt1 = (T + 1) * 64;

        short8 aF[4], bF[4];

        // ---- phase 1: kk0, m0-3 ; issue T+1 k0 stages (4 loads) ----
        LDA4(cb, 0, 0);
        LDB4(cb, 0);
        if (pf) { STAGE_A(nb, 0, kt1); STAGE_B(nb, 0, kt1); }
        __builtin_amdgcn_s_barrier();
        LGKM0_FENCE();
        __builtin_amdgcn_s_setprio(1);
        MFMA16(0);
        __builtin_amdgcn_s_setprio(0);
        __builtin_amdgcn_s_barrier();

        // ---- phase 2: kk0, m4-7 ; issue T+1 k1 stages (4 loads) ----
        LDA4(cb, 0, 4);
        if (pf) { STAGE_A(nb, 1, kt1); STAGE_B(nb, 1, kt1); }
        __builtin_amdgcn_s_barrier();
        LGKM0_FENCE();
        __builtin_amdgcn_s_setprio(1);
        MFMA16(4);
        __builtin_amdgcn_s_setprio(0);
        if (pf) { asm volatile("s_waitcnt vmcnt(8)" ::: "memory"); }  // proves T's k1
        else    { asm volatile("s_waitcnt vmcnt(0)" ::: "memory"); }
        __builtin_amdgcn_sched_barrier(0);
        __builtin_amdgcn_s_barrier();

        // ---- phase 3: kk1, m0-3 ----
        LDA4(cb, 1, 0);
        LDB4(cb, 1);
        __builtin_amdgcn_s_barrier();
        LGKM0_FENCE();
        __builtin_amdgcn_s_setprio(1);
        MFMA16(0);
        __builtin_amdgcn_s_setprio(0);
        __builtin_amdgcn_s_barrier();

        // ---- phase 4: kk1, m4-7 ----
        LDA4(cb, 1, 4);
        __builtin_amdgcn_s_barrier();
        LGKM0_FENCE();
        __builtin_amdgcn_s_setprio(1);
        MFMA16(4);
        __builtin_amdgcn_s_setprio(0);
        if (pf) {
            asm volatile("s_waitcnt vmcnt(4)" ::: "memory");  // proves T+1's k0
            __builtin_amdgcn_sched_barrier(0);
        }
        __builtin_amdgcn_s_barrier();
    }

    // ---- epilogue: C layout col=lane&15, row=(lane>>4)*4+reg ----
#pragma unroll
    for (int m = 0; m < 8; ++m) {
#pragma unroll
        for (int n = 0; n < 4; ++n) {
#pragma unroll
            for (int r = 0; r < 4; ++r) {
                const int gm = m0 + wm * 128 + m * 16 + ((lane >> 4) << 2) + r;
                if (gm < M) {
                    const int gc = n0 + wn * 64 + n * 16 + (lane & 15);
                    if (MODE == 0) {
                        const int t = gc >> 10;
                        const int h = (gc >> 6) & 15;
                        const int d = gc & 63;
                        const u32 bb = (u32)gm / 3137u;
                        const u32 nn = (u32)gm - bb * 3137u;
                        u16* dst = (t == 0) ? q_out : (t == 1) ? k_out : v_out;
                        dst[(((size_t)(bb * 16 + h)) * NTOK + nn) * 64 + d] =
                            f2b(acc[m][n][r]);
                    } else {
                        f_out[(size_t)gm * 1024 + gc] = acc[m][n][r] + bias[gc];
                    }
                }
            }
        }
    }
#undef STAGE_A
#undef STAGE_B
#undef LDA4
#undef LDB4
#undef MFMA16
#undef LGKM0_FENCE
}

// ---------- cls attention, split-K flash: part (1024 blocks) + fin (128 blocks) ----------
#define CSZ 393
__global__ __launch_bounds__(256) void attn_cls_part(const u16* __restrict__ qb,
                                                     const u16* __restrict__ kb,
                                                     const u16* __restrict__ vb,
                                                     float* __restrict__ part) {
    const int bid = blockIdx.x;
    const int bh = bid >> 3, c = bid & 7;
    const size_t base = (size_t)bh * NTOK * 64;
    const int tid = threadIdx.x, lane = tid & 63, wid = tid >> 6;
    const int j0 = c * CSZ;
    const int cnt = min(NTOK - j0, CSZ);

    __shared__ float qs[64];
    __shared__ float sc[CSZ];
    __shared__ float redbuf[8];
    __shared__ float ored[4][64];

    if (tid < 64) qs[tid] = b2f(qb[base + tid]);
    __syncthreads();

    for (int j = tid; j < cnt; j += 256) {
        const u16* kr = kb + base + (size_t)(j0 + j) * 64;
        float acc = 0.f;
#pragma unroll
        for (int c2 = 0; c2 < 8; ++c2) {
            short8 v8 = *(const short8*)(kr + c2 * 8);
#pragma unroll
            for (int t = 0; t < 8; ++t) acc += qs[c2 * 8 + t] * b2f((u16)v8[t]);
        }
        sc[j] = acc * 0.125f;
    }
    __syncthreads();

    float mx = -1e30f;
    for (int j = tid; j < cnt; j += 256) mx = fmaxf(mx, sc[j]);
#pragma unroll
    for (int m = 32; m >= 1; m >>= 1) mx = fmaxf(mx, __shfl_xor(mx, m));
    if (lane == 0) redbuf[wid] = mx;
    __syncthreads();
    mx = fmaxf(fmaxf(redbuf[0], redbuf[1]), fmaxf(redbuf[2], redbuf[3]));

    float sum = 0.f;
    for (int j = tid; j < cnt; j += 256) {
        float p = exp2f((sc[j] - mx) * LOG2E);
        sc[j] = p;
        sum += p;
    }
#pragma unroll
    for (int m = 32; m >= 1; m >>= 1) sum += __shfl_xor(sum, m);
    if (lane == 0) redbuf[4 + wid] = sum;
    __syncthreads();
    const float tot = redbuf[4] + redbuf[5] + redbuf[6] + redbuf[7];

    const int d = tid & 63, g = tid >> 6;
    float o = 0.f;
    for (int j = g; j < cnt; j += 4)
        o += sc[j] * b2f(vb[base + (size_t)(j0 + j) * 64 + d]);
    ored[g][d] = o;
    __syncthreads();

    float* pb = part + (size_t)bid * 66;
    if (tid < 64) pb[2 + tid] = ored[0][tid] + ored[1][tid] + ored[2][tid] + ored[3][tid];
    else if (tid == 64) pb[0] = mx;
    else if (tid == 65) pb[1] = tot;
}

__global__ __launch_bounds__(64) void attn_cls_fin(const float* __restrict__ part,
                                                   u16* __restrict__ attnb) {
    const int bh = blockIdx.x, d = threadIdx.x;
    const int bb = bh >> 4, h = bh & 15;
    float m = -1e30f;
#pragma unroll
    for (int c = 0; c < 8; ++c) m = fmaxf(m, part[(size_t)(bh * 8 + c) * 66]);
    float t = 0.f, o = 0.f;
#pragma unroll
    for (int c = 0; c < 8; ++c) {
        const float* pb = part + (size_t)(bh * 8 + c) * 66;
        const float w = exp2f((pb[0] - m) * LOG2E);
        t += w * pb[1];
        o += w * pb[2 + d];
    }
    attnb[(size_t)bb * NTOK * 1024 + h * 64 + d] = f2b(o / t);
}

// ---------- spatial attention: 2048 blocks, 81.5KB LDS -> 2 blocks/CU ----------
// K zero-padded to 208 rows (no per-element masking); softmax uses raw scores with
// fused scale C=0.125*log2e: p = exp2(fma(s,C,-mx*C)); pad cols corrected in the sum.
__global__ __launch_bounds__(256) void attn_spatial(const u16* __restrict__ qb,
                                                    const u16* __restrict__ kb,
                                                    const u16* __restrict__ vb,
                                                    u16* __restrict__ attnb) {
    const int blk = blockIdx.x;
    const int bh = blk >> 4, fi = blk & 15;
    const int bb = bh >> 4, h = bh & 15;
    const int tid = threadIdx.x, lane = tid & 63, wid = tid >> 6;
    const int hi = lane >> 4, lo = lane & 15;
    const size_t kvbase = (size_t)bh * NTOK * 64;

    __shared__ u16 Kl[208 * 68];      // K rows (197 real + 11 zero), stride 68
    __shared__ u16 Vt[64 * 208];      // V transposed, stride 208 (pad cols zero)
    __shared__ u16 Pl[4 * 16 * 208];  // per-wave P tile; doubles as V row-major Ptmp

    u16* Ptmp = Pl;
    const short8 z8 = {0, 0, 0, 0, 0, 0, 0, 0};
    for (int idx = tid; idx < 208 * 8; idx += 256) {
        const int j = idx >> 3, c = idx & 7;
        short8 kval = z8;
        if (j < 197) {
            const int n = (j == 0) ? 0 : (1 + fi * 196 + (j - 1));
            kval = *(const short8*)(kb + kvbase + (size_t)n * 64 + c * 8);
            *(short8*)(Ptmp + ((j * 64 + c * 8) ^ ((j & 7) << 3))) =
                *(const short8*)(vb + kvbase + (size_t)n * 64 + c * 8);
        }
        *(short8*)(Kl + j * 68 + c * 8) = kval;
    }
    __syncthreads();
#pragma unroll
    for (int c = 0; c < 8; ++c) {
        if (tid < 197) {
            short8 v8 = *(const short8*)(Ptmp + ((tid * 64 + c * 8) ^ ((tid & 7) << 3)));
#pragma unroll
            for (int t = 0; t < 8; ++t) Vt[(c * 8 + t) * 208 + tid] = (u16)v8[t];
        }
    }
    for (int idx = tid; idx < 64 * 11; idx += 256)
        Vt[(idx / 11) * 208 + 197 + (idx % 11)] = 0;
    __syncthreads();

    u16* pl = Pl + wid * 16 * 208;
    const f32x4 zf = {0.f, 0.f, 0.f, 0.f};

    for (int mf = wid; mf < 13; mf += 4) {
        int qr = mf * 16 + lo; if (qr > 195) qr = 195;
        const u16* qp = qb + kvbase + (size_t)(1 + fi * 196 + qr) * 64 + hi * 8;
        const short8 a0 = *(const short8*)(qp);
        const short8 a1 = *(const short8*)(qp + 32);

        f32x4 s[13];
#pragma unroll
        for (int nf = 0; nf < 13; ++nf) s[nf] = zf;
#pragma unroll
        for (int nf = 0; nf < 13; ++nf) {
            const u16* kp = Kl + (nf * 16 + lo) * 68 + hi * 8;
            const short8 b0 = *(const short8*)(kp);
            const short8 b1 = *(const short8*)(kp + 32);
            s[nf] = __builtin_amdgcn_mfma_f32_16x16x32_bf16(a0, b0, s[nf], 0, 0, 0);
            s[nf] = __builtin_amdgcn_mfma_f32_16x16x32_bf16(a1, b1, s[nf], 0, 0, 0);
        }

        float rls[4];
#pragma unroll
        for (int reg = 0; reg < 4; ++reg) {
            float mx = s[0][reg];
#pragma unroll
            for (int nf = 1; nf < 13; ++nf) mx = fmaxf(mx, s[nf][reg]);
            mx = fmaxf(mx, __shfl_xor(mx, 1));
            mx = fmaxf(mx, __shfl_xor(mx, 2));
            mx = fmaxf(mx, __shfl_xor(mx, 4));
            mx = fmaxf(mx, __shfl_xor(mx, 8));
            const float mC = mx * SCL2;
            float sum = 0.f;
#pragma unroll
            for (int nf = 0; nf < 13; ++nf) {
                const float p = exp2f(fmaf(s[nf][reg], SCL2, -mC));
                s[nf][reg] = p;
                sum += p;
            }
            sum += __shfl_xor(sum, 1);
            sum += __shfl_xor(sum, 2);
            sum += __shfl_xor(sum, 4);
            sum += __shfl_xor(sum, 8);
            rls[reg] = 1.0f / (sum - 11.0f * exp2f(-mC));
        }

#pragma unroll
        for (int nf = 0; nf < 13; ++nf)
#pragma unroll
            for (int reg = 0; reg < 4; ++reg)
                pl[(hi * 4 + reg) * 208 + nf * 16 + lo] = f2b(s[nf][reg]);

        f32x4 o[4];
#pragma unroll
        for (int i = 0; i < 4; ++i) o[i] = zf;
#pragma unroll
        for (int kk = 0; kk < 6; ++kk) {
            const short8 pa = *(const short8*)(pl + lo * 208 + kk * 32 + hi * 8);
#pragma unroll
            for (int nf2 = 0; nf2 < 4; ++nf2) {
                const short8 bvv =
                    *(const short8*)(Vt + (nf2 * 16 + lo) * 208 + kk * 32 + hi * 8);
                o[nf2] = __builtin_amdgcn_mfma_f32_16x16x32_bf16(pa, bvv, o[nf2], 0, 0, 0);
            }
        }
        {   // tail: keys 192..207 (hi<2 lanes carry them; hi>=2 zeroed)
            const u16* pap = pl + lo * 208 + 192 + (hi < 2 ? hi * 8 : 0);
            short8 pa = *(const short8*)pap;
            if (hi >= 2) pa = z8;
#pragma unroll
            for (int nf2 = 0; nf2 < 4; ++nf2) {
                const u16* bvp = Vt + (nf2 * 16 + lo) * 208 + 192 + (hi < 2 ? hi * 8 : 0);
                short8 bvv = *(const short8*)bvp;
                if (hi >= 2) bvv = z8;
                o[nf2] = __builtin_amdgcn_mfma_f32_16x16x32_bf16(pa, bvv, o[nf2], 0, 0, 0);
            }
        }

#pragma unroll
        for (int nf2 = 0; nf2 < 4; ++nf2)
#pragma unroll
            for (int reg = 0; reg < 4; ++reg) {
                const int r = mf * 16 + hi * 4 + reg;
                if (r < 196) {
                    const int d = nf2 * 16 + lo;
                    const size_t nn = 1 + fi * 196 + r;
                    attnb[((size_t)bb * NTOK + nn) * 1024 + h * 64 + d] =
                        f2b(o[nf2][reg] * rls[reg]);
                }
            }
    }
}

// ---------- launch ----------
extern "C" void kernel_launch(void* const* d_in, const int* in_sizes, int n_in,
                              void* d_out, int out_size, void* d_ws, size_t ws_size,
                              hipStream_t stream) {
    const float* x = (const float*)d_in[0];
    const float* w_qkv = (const float*)d_in[1];
    const float* w_out = (const float*)d_in[2];
    const float* b_out = (const float*)d_in[3];

    const size_t need = ((size_t)QE * 2 + 3145728 + 1048576) * 2;
    if (ws_size < need) {
        hipMemsetAsync(d_out, 0, (size_t)out_size * 4, stream);
        return;
    }

    u16* vb = (u16*)d_ws;
    u16* xab = vb + QE;
    u16* wqb = xab + QE;
    u16* wob = wqb + 3145728;
    u16* qb = (u16*)d_out;
    u16* kb = qb + QE;
    float* outf = (float*)d_out;
    float* clsp = (float*)wqb;

    cvt_kernel<<<2048, 256, 0, stream>>>(x, xab, QE / 4);
    cvt_kernel<<<2048, 256, 0, stream>>>(w_qkv, wqb, 3145728 / 4);
    cvt_kernel<<<1024, 256, 0, stream>>>(w_out, wob, 1048576 / 4);

    gemm256<0><<<dim3(12, 99), 512, 0, stream>>>(xab, wqb, qb, kb, vb, nullptr,
                                                 nullptr, MROWS);
    attn_cls_part<<<1024, 256, 0, stream>>>(qb, kb, vb, clsp);
    attn_cls_fin<<<128, 64, 0, stream>>>(clsp, xab);
    attn_spatial<<<2048, 256, 0, stream>>>(qb, kb, vb, xab);
    gemm256<1><<<dim3(4, 99), 512, 0, stream>>>(xab, wob, nullptr, nullptr, nullptr,
                                                b_out, outf, MROWS);
}

// Round 7
// 457.199 us; speedup vs baseline: 1.1314x; 1.1314x over previous
//
#include <hip/hip_runtime.h>
#include <cstdint>
#include <cstddef>

#define DEVINL __device__ __forceinline__

typedef __attribute__((ext_vector_type(8))) short short8;
typedef __attribute__((ext_vector_type(4))) float f32x4;
typedef unsigned short u16;
typedef unsigned int u32;

// ---------- bf16 helpers (RNE) ----------
DEVINL u16 f2b(float f) {
    u32 u = __float_as_uint(f);
    u32 r = (u + 0x7fffu + ((u >> 16) & 1u)) >> 16;
    return (u16)r;
}
DEVINL float b2f(u16 h) { return __uint_as_float(((u32)h) << 16); }

DEVINL void gl_lds16(const void* g, void* l) {
    __builtin_amdgcn_global_load_lds(
        (const __attribute__((address_space(1))) void*)g,
        (__attribute__((address_space(3))) void*)l, 16, 0, 0);
}

// ---------- constants ----------
#define MROWS   25096
#define NTOK    3137
#define QE      25698304
#define LOG2E   1.4426950408889634f
#define SCL2    0.1803368801111204f   /* 0.125 * log2(e) */

// ---------- fp32 -> bf16 conversion ----------
__global__ __launch_bounds__(256) void cvt_kernel(const float* __restrict__ in,
                                                  u16* __restrict__ out, int n4) {
    int i = blockIdx.x * blockDim.x + threadIdx.x;
    int stride = gridDim.x * blockDim.x;
    for (int j = i; j < n4; j += stride) {
        float4 v = ((const float4*)in)[j];
        ushort4 o;
        o.x = f2b(v.x); o.y = f2b(v.y); o.z = f2b(v.z); o.w = f2b(v.w);
        ((ushort4*)out)[j] = o;
    }
}

// ================= 256x256 bf16 MFMA GEMM (round-4 proven schedule) =================
#define LDS_BUF 32768
#define NTILES  16

template <int MODE>
__global__ __launch_bounds__(512, 2) void gemm256(const u16* __restrict__ A,
                                                  const u16* __restrict__ B,
                                                  u16* __restrict__ q_out,
                                                  u16* __restrict__ k_out,
                                                  u16* __restrict__ v_out,
                                                  const float* __restrict__ bias,
                                                  float* __restrict__ f_out, int M) {
    __shared__ u16 lds[2 * LDS_BUF];   // 128 KiB
    const int tid = threadIdx.x, lane = tid & 63, w = tid >> 6;
    const int Mm1 = M - 1;

    const u32 nwg = gridDim.x * gridDim.y;
    const u32 orig = blockIdx.y * gridDim.x + blockIdx.x;
    const u32 q8 = nwg >> 3, r8 = nwg & 7, xcd = orig & 7, rest = orig >> 3;
    const u32 wg = (xcd < r8 ? xcd * (q8 + 1) : r8 * (q8 + 1) + (xcd - r8) * q8) + rest;
    const int m0 = (int)(wg / gridDim.x) * 256;
    const int n0 = (int)(wg % gridDim.x) * 256;

    const int wm = w >> 2, wn = w & 3;

    const int stRow = lane >> 2;
    const int stCol = (((lane & 3) ^ ((lane >> 3) & 3)) << 3);

    const int slotOff = (((lane >> 4) ^ ((lane >> 1) & 3)) << 3);
    const int rdA = (wm * 128 + (lane & 15)) * 32 + slotOff;
    const int rdB = (wn * 64 + (lane & 15)) * 32 + slotOff + 16384;

#define STAGE_A(NB, KK, KT) do {                                              \
    _Pragma("unroll") for (int j_ = 0; j_ < 2; ++j_) {                        \
        const int c_ = (w << 1) | j_;                                         \
        int r_ = m0 + c_ * 16 + stRow; if (r_ > Mm1) r_ = Mm1;                \
        gl_lds16(A + (size_t)r_ * 1024 + (KT) + (KK) * 32 + stCol,            \
                 lds + (NB) + (KK) * 8192 + c_ * 512);                        \
    } } while (0)

#define STAGE_B(NB, KK, KT) do {                                              \
    _Pragma("unroll") for (int j_ = 0; j_ < 2; ++j_) {                        \
        const int c_ = (w << 1) | j_;                                         \
        const int r_ = n0 + c_ * 16 + stRow;                                  \
        gl_lds16(B + (size_t)r_ * 1024 + (KT) + (KK) * 32 + stCol,            \
                 lds + (NB) + 16384 + (KK) * 8192 + c_ * 512);                \
    } } while (0)

#define LDA4(CB, KK, MB) do {                                                 \
    _Pragma("unroll") for (int i_ = 0; i_ < 4; ++i_)                          \
        aF[i_] = *(const short8*)&lds[(CB) + (KK) * 8192 + rdA +              \
                                      ((MB) + i_) * 16 * 32];                 \
    } while (0)

#define LDB4(CB, KK) do {                                                     \
    _Pragma("unroll") for (int i_ = 0; i_ < 4; ++i_)                          \
        bF[i_] = *(const short8*)&lds[(CB) + (KK) * 8192 + rdB +              \
                                      i_ * 16 * 32];                          \
    } while (0)

#define MFMA16(MB) do {                                                       \
    _Pragma("unroll") for (int i_ = 0; i_ < 4; ++i_)                          \
        _Pragma("unroll") for (int n_ = 0; n_ < 4; ++n_)                      \
            acc[(MB) + i_][n_] = __builtin_amdgcn_mfma_f32_16x16x32_bf16(     \
                aF[i_], bF[n_], acc[(MB) + i_][n_], 0, 0, 0);                 \
    } while (0)

#define LGKM0_FENCE() do {                                                    \
    asm volatile("s_waitcnt lgkmcnt(0)" ::: "memory");                        \
    __builtin_amdgcn_sched_barrier(0); } while (0)

    f32x4 acc[8][4];
    const f32x4 zf = {0.f, 0.f, 0.f, 0.f};
#pragma unroll
    for (int i = 0; i < 8; ++i)
#pragma unroll
        for (int j = 0; j < 4; ++j) acc[i][j] = zf;

    STAGE_A(0, 0, 0);
    STAGE_B(0, 0, 0);
    STAGE_A(0, 1, 0);
    STAGE_B(0, 1, 0);
    asm volatile("s_waitcnt vmcnt(4)" ::: "memory");
    __builtin_amdgcn_sched_barrier(0);
    __builtin_amdgcn_s_barrier();

    for (int T = 0; T < NTILES; ++T) {
        const int cb = (T & 1) * LDS_BUF;
        const int nb = ((T + 1) & 1) * LDS_BUF;
        const bool pf = (T < NTILES - 1);
        const int kt1 = (T + 1) * 64;

        short8 aF[4], bF[4];

        // ---- phase 1: kk0, m0-3 ----
        LDA4(cb, 0, 0);
        LDB4(cb, 0);
        if (pf) STAGE_A(nb, 0, kt1);
        __builtin_amdgcn_s_barrier();
        LGKM0_FENCE();
        __builtin_amdgcn_s_setprio(1);
        MFMA16(0);
        __builtin_amdgcn_s_setprio(0);
        __builtin_amdgcn_s_barrier();

        // ---- phase 2: kk0, m4-7 ----
        LDA4(cb, 0, 4);
        if (pf) STAGE_B(nb, 0, kt1);
        __builtin_amdgcn_s_barrier();
        LGKM0_FENCE();
        __builtin_amdgcn_s_setprio(1);
        MFMA16(4);
        __builtin_amdgcn_s_setprio(0);
        if (pf) { asm volatile("s_waitcnt vmcnt(4)" ::: "memory"); }
        else    { asm volatile("s_waitcnt vmcnt(0)" ::: "memory"); }
        __builtin_amdgcn_sched_barrier(0);
        __builtin_amdgcn_s_barrier();

        // ---- phase 3: kk1, m0-3 ----
        LDA4(cb, 1, 0);
        LDB4(cb, 1);
        if (pf) STAGE_A(nb, 1, kt1);
        __builtin_amdgcn_s_barrier();
        LGKM0_FENCE();
        __builtin_amdgcn_s_setprio(1);
        MFMA16(0);
        __builtin_amdgcn_s_setprio(0);
        __builtin_amdgcn_s_barrier();

        // ---- phase 4: kk1, m4-7 ----
        LDA4(cb, 1, 4);
        if (pf) STAGE_B(nb, 1, kt1);
        __builtin_amdgcn_s_barrier();
        LGKM0_FENCE();
        __builtin_amdgcn_s_setprio(1);
        MFMA16(4);
        __builtin_amdgcn_s_setprio(0);
        if (pf) {
            asm volatile("s_waitcnt vmcnt(4)" ::: "memory");
            __builtin_amdgcn_sched_barrier(0);
        }
        __builtin_amdgcn_s_barrier();
    }

#pragma unroll
    for (int m = 0; m < 8; ++m) {
#pragma unroll
        for (int n = 0; n < 4; ++n) {
#pragma unroll
            for (int r = 0; r < 4; ++r) {
                const int gm = m0 + wm * 128 + m * 16 + ((lane >> 4) << 2) + r;
                if (gm < M) {
                    const int gc = n0 + wn * 64 + n * 16 + (lane & 15);
                    if (MODE == 0) {
                        const int t = gc >> 10;
                        const int h = (gc >> 6) & 15;
                        const int d = gc & 63;
                        const u32 bb = (u32)gm / 3137u;
                        const u32 nn = (u32)gm - bb * 3137u;
                        u16* dst = (t == 0) ? q_out : (t == 1) ? k_out : v_out;
                        dst[(((size_t)(bb * 16 + h)) * NTOK + nn) * 64 + d] =
                            f2b(acc[m][n][r]);
                    } else {
                        f_out[(size_t)gm * 1024 + gc] = acc[m][n][r] + bias[gc];
                    }
                }
            }
        }
    }
#undef STAGE_A
#undef STAGE_B
#undef LDA4
#undef LDB4
#undef MFMA16
#undef LGKM0_FENCE
}

// ---------- cls attention, split-K flash ----------
#define CSZ 393
__global__ __launch_bounds__(256) void attn_cls_part(const u16* __restrict__ qb,
                                                     const u16* __restrict__ kb,
                                                     const u16* __restrict__ vb,
                                                     float* __restrict__ part) {
    const int bid = blockIdx.x;
    const int bh = bid >> 3, c = bid & 7;
    const size_t base = (size_t)bh * NTOK * 64;
    const int tid = threadIdx.x, lane = tid & 63, wid = tid >> 6;
    const int j0 = c * CSZ;
    const int cnt = min(NTOK - j0, CSZ);

    __shared__ float qs[64];
    __shared__ float sc[CSZ];
    __shared__ float redbuf[8];
    __shared__ float ored[4][64];

    if (tid < 64) qs[tid] = b2f(qb[base + tid]);
    __syncthreads();

    for (int j = tid; j < cnt; j += 256) {
        const u16* kr = kb + base + (size_t)(j0 + j) * 64;
        float acc = 0.f;
#pragma unroll
        for (int c2 = 0; c2 < 8; ++c2) {
            short8 v8 = *(const short8*)(kr + c2 * 8);
#pragma unroll
            for (int t = 0; t < 8; ++t) acc += qs[c2 * 8 + t] * b2f((u16)v8[t]);
        }
        sc[j] = acc * 0.125f;
    }
    __syncthreads();

    float mx = -1e30f;
    for (int j = tid; j < cnt; j += 256) mx = fmaxf(mx, sc[j]);
#pragma unroll
    for (int m = 32; m >= 1; m >>= 1) mx = fmaxf(mx, __shfl_xor(mx, m));
    if (lane == 0) redbuf[wid] = mx;
    __syncthreads();
    mx = fmaxf(fmaxf(redbuf[0], redbuf[1]), fmaxf(redbuf[2], redbuf[3]));

    float sum = 0.f;
    for (int j = tid; j < cnt; j += 256) {
        float p = exp2f((sc[j] - mx) * LOG2E);
        sc[j] = p;
        sum += p;
    }
#pragma unroll
    for (int m = 32; m >= 1; m >>= 1) sum += __shfl_xor(sum, m);
    if (lane == 0) redbuf[4 + wid] = sum;
    __syncthreads();
    const float tot = redbuf[4] + redbuf[5] + redbuf[6] + redbuf[7];

    const int d = tid & 63, g = tid >> 6;
    float o = 0.f;
    for (int j = g; j < cnt; j += 4)
        o += sc[j] * b2f(vb[base + (size_t)(j0 + j) * 64 + d]);
    ored[g][d] = o;
    __syncthreads();

    float* pb = part + (size_t)bid * 66;
    if (tid < 64) pb[2 + tid] = ored[0][tid] + ored[1][tid] + ored[2][tid] + ored[3][tid];
    else if (tid == 64) pb[0] = mx;
    else if (tid == 65) pb[1] = tot;
}

__global__ __launch_bounds__(64) void attn_cls_fin(const float* __restrict__ part,
                                                   u16* __restrict__ attnb) {
    const int bh = blockIdx.x, d = threadIdx.x;
    const int bb = bh >> 4, h = bh & 15;
    float m = -1e30f;
#pragma unroll
    for (int c = 0; c < 8; ++c) m = fmaxf(m, part[(size_t)(bh * 8 + c) * 66]);
    float t = 0.f, o = 0.f;
#pragma unroll
    for (int c = 0; c < 8; ++c) {
        const float* pb = part + (size_t)(bh * 8 + c) * 66;
        const float w = exp2f((pb[0] - m) * LOG2E);
        t += w * pb[1];
        o += w * pb[2 + d];
    }
    attnb[(size_t)bb * NTOK * 1024 + h * 64 + d] = f2b(o / t);
}

// ---------- spatial attention: swapped-QK, in-register P, 52 KB LDS -> 3 blocks/CU ----
// S^T = mfma(K, Q): lane holds S[k = nf*16+4*hi+reg][q = lane&15].
// Softmax per q: in-lane reduce + shfl_xor(16,32). P normalized in-register, packed
// bf16 via v_cvt_pk_bf16_f32; PV A-frags gathered with 8 shfl per kk. No P LDS tile.
// Kl: [208][64] XOR-swizzled (slot ^= lo&7) -> conflict-free QK reads.
__global__ __launch_bounds__(256, 3) void attn_spatial(const u16* __restrict__ qb,
                                                       const u16* __restrict__ kb,
                                                       const u16* __restrict__ vb,
                                                       u16* __restrict__ attnb) {
    const int blk = blockIdx.x;
    const int bh = blk >> 4, fi = blk & 15;
    const int bb = bh >> 4, h = bh & 15;
    const int tid = threadIdx.x, lane = tid & 63, wid = tid >> 6;
    const int hi = lane >> 4, lo = lane & 15;
    const size_t kvbase = (size_t)bh * NTOK * 64;

    __shared__ u16 Kl[208 * 64];   // XOR-swizzled K rows (197 real + 11 zero)
    __shared__ u16 Vt[64 * 208];   // V transposed, stride 208 (pad cols zero)

    const short8 z8 = {0, 0, 0, 0, 0, 0, 0, 0};

    // staging: K swizzled b128 writes; V transposed via rotated scalar writes
    for (int idx = tid; idx < 208 * 8; idx += 256) {
        const int j = idx >> 3, c = idx & 7;
        short8 kval = z8;
        if (j < 197) {
            const int n = (j == 0) ? 0 : (1 + fi * 196 + (j - 1));
            kval = *(const short8*)(kb + kvbase + (size_t)n * 64 + c * 8);
            const short8 v8 = *(const short8*)(vb + kvbase + (size_t)n * 64 + c * 8);
#pragma unroll
            for (int t0 = 0; t0 < 8; ++t0) {
                const int t = (t0 + c) & 7;
                Vt[(c * 8 + t) * 208 + j] = (u16)v8[t];
            }
        } else {
#pragma unroll
            for (int t = 0; t < 8; ++t) Vt[(c * 8 + t) * 208 + j] = 0;
        }
        *(short8*)(Kl + ((j * 64 + c * 8) ^ ((j & 7) << 3))) = kval;
    }
    __syncthreads();

    const int ksw = (lo & 7) << 3;
    const int src0 = lo + ((hi & 1) << 5);
    const int src1 = src0 + 16;
    const f32x4 zf = {0.f, 0.f, 0.f, 0.f};

    for (int mf = wid; mf < 13; mf += 4) {
        // Q as B-operand: lane holds Q row q=lo, k-chunk hi*8
        int qr = mf * 16 + lo; if (qr > 195) qr = 195;
        const u16* qp = qb + kvbase + (size_t)(1 + fi * 196 + qr) * 64 + hi * 8;
        const short8 qb0 = *(const short8*)(qp);
        const short8 qb1 = *(const short8*)(qp + 32);

        // QK^T swapped: s[nf] holds S[k-rows nf*16+4hi+reg][q=lo]
        f32x4 s[13];
#pragma unroll
        for (int nf = 0; nf < 13; ++nf) s[nf] = zf;
#pragma unroll
        for (int nf = 0; nf < 13; ++nf) {
            const int e0 = (nf * 16 + lo) * 64 + hi * 8;
            const short8 a0 = *(const short8*)(Kl + (e0 ^ ksw));
            const short8 a1 = *(const short8*)(Kl + ((e0 + 32) ^ ksw));
            s[nf] = __builtin_amdgcn_mfma_f32_16x16x32_bf16(a0, qb0, s[nf], 0, 0, 0);
            s[nf] = __builtin_amdgcn_mfma_f32_16x16x32_bf16(a1, qb1, s[nf], 0, 0, 0);
        }

        // softmax along k for this lane's q (= lo)
        float mx = s[0][0];
#pragma unroll
        for (int nf = 0; nf < 13; ++nf)
#pragma unroll
            for (int reg = 0; reg < 4; ++reg) mx = fmaxf(mx, s[nf][reg]);
        mx = fmaxf(mx, __shfl_xor(mx, 16));
        mx = fmaxf(mx, __shfl_xor(mx, 32));
        const float mC = mx * SCL2;
        float sum = 0.f;
#pragma unroll
        for (int nf = 0; nf < 13; ++nf)
#pragma unroll
            for (int reg = 0; reg < 4; ++reg) {
                const float p = exp2f(fmaf(s[nf][reg], SCL2, -mC));
                s[nf][reg] = p;
                sum += p;
            }
        sum += __shfl_xor(sum, 16);
        sum += __shfl_xor(sum, 32);
        const float rls = 1.0f / (sum - 11.0f * exp2f(-mC));

        // normalize + pack: w0[nf] = bf16(p[4hi],p[4hi+1]), w1[nf] = bf16(p[4hi+2],p[4hi+3])
        u32 w0[13], w1[13];
#pragma unroll
        for (int nf = 0; nf < 13; ++nf) {
            const float p0 = s[nf][0] * rls, p1 = s[nf][1] * rls;
            const float p2 = s[nf][2] * rls, p3 = s[nf][3] * rls;
            asm("v_cvt_pk_bf16_f32 %0, %1, %2" : "=v"(w0[nf]) : "v"(p0), "v"(p1));
            asm("v_cvt_pk_bf16_f32 %0, %1, %2" : "=v"(w1[nf]) : "v"(p2), "v"(p3));
        }

        // PV: A-frag = P row q=lo, k window kk*32+8hi..+7, gathered via shfl
        f32x4 o[4];
#pragma unroll
        for (int i = 0; i < 4; ++i) o[i] = zf;
#pragma unroll
        for (int kk = 0; kk < 7; ++kk) {
            u32 x0, x1, x2, x3;
            if (kk < 6) {
                const u32 aA0 = __shfl(w0[2 * kk], src0), aA1 = __shfl(w1[2 * kk], src0);
                const u32 aA2 = __shfl(w0[2 * kk], src1), aA3 = __shfl(w1[2 * kk], src1);
                const u32 aB0 = __shfl(w0[2 * kk + 1], src0), aB1 = __shfl(w1[2 * kk + 1], src0);
                const u32 aB2 = __shfl(w0[2 * kk + 1], src1), aB3 = __shfl(w1[2 * kk + 1], src1);
                const bool lh = hi < 2;
                x0 = lh ? aA0 : aB0; x1 = lh ? aA1 : aB1;
                x2 = lh ? aA2 : aB2; x3 = lh ? aA3 : aB3;
            } else {  // kk=6: k 192..207 real (hi<2); hi>=2 zero
                const u32 aA0 = __shfl(w0[12], src0), aA1 = __shfl(w1[12], src0);
                const u32 aA2 = __shfl(w0[12], src1), aA3 = __shfl(w1[12], src1);
                const bool lh = hi < 2;
                x0 = lh ? aA0 : 0u; x1 = lh ? aA1 : 0u;
                x2 = lh ? aA2 : 0u; x3 = lh ? aA3 : 0u;
            }
            union { u32 u[4]; short8 v; } pu;
            pu.u[0] = x0; pu.u[1] = x1; pu.u[2] = x2; pu.u[3] = x3;
            const short8 pa = pu.v;
#pragma unroll
            for (int nf2 = 0; nf2 < 4; ++nf2) {
                short8 bv = z8;
                if (kk < 6 || hi < 2)
                    bv = *(const short8*)(Vt + (nf2 * 16 + lo) * 208 + kk * 32 + hi * 8);
                o[nf2] = __builtin_amdgcn_mfma_f32_16x16x32_bf16(pa, bv, o[nf2], 0, 0, 0);
            }
        }

        // epilogue: O[q = mf*16+4hi+reg][d = nf2*16+lo], already normalized
#pragma unroll
        for (int nf2 = 0; nf2 < 4; ++nf2)
#pragma unroll
            for (int reg = 0; reg < 4; ++reg) {
                const int r = mf * 16 + hi * 4 + reg;
                if (r < 196) {
                    const int d = nf2 * 16 + lo;
                    const size_t nn = 1 + fi * 196 + r;
                    attnb[((size_t)bb * NTOK + nn) * 1024 + h * 64 + d] =
                        f2b(o[nf2][reg]);
                }
            }
    }
}

// ---------- launch ----------
extern "C" void kernel_launch(void* const* d_in, const int* in_sizes, int n_in,
                              void* d_out, int out_size, void* d_ws, size_t ws_size,
                              hipStream_t stream) {
    const float* x = (const float*)d_in[0];
    const float* w_qkv = (const float*)d_in[1];
    const float* w_out = (const float*)d_in[2];
    const float* b_out = (const float*)d_in[3];

    const size_t need = ((size_t)QE * 2 + 3145728 + 1048576) * 2;
    if (ws_size < need) {
        hipMemsetAsync(d_out, 0, (size_t)out_size * 4, stream);
        return;
    }

    u16* vb = (u16*)d_ws;
    u16* xab = vb + QE;
    u16* wqb = xab + QE;
    u16* wob = wqb + 3145728;
    u16* qb = (u16*)d_out;
    u16* kb = qb + QE;
    float* outf = (float*)d_out;
    float* clsp = (float*)wqb;

    cvt_kernel<<<2048, 256, 0, stream>>>(x, xab, QE / 4);
    cvt_kernel<<<2048, 256, 0, stream>>>(w_qkv, wqb, 3145728 / 4);
    cvt_kernel<<<1024, 256, 0, stream>>>(w_out, wob, 1048576 / 4);

    gemm256<0><<<dim3(12, 99), 512, 0, stream>>>(xab, wqb, qb, kb, vb, nullptr,
                                                 nullptr, MROWS);
    attn_cls_part<<<1024, 256, 0, stream>>>(qb, kb, vb, clsp);
    attn_cls_fin<<<128, 64, 0, stream>>>(clsp, xab);
    attn_spatial<<<2048, 256, 0, stream>>>(qb, kb, vb, xab);
    gemm256<1><<<dim3(4, 99), 512, 0, stream>>>(xab, wob, nullptr, nullptr, nullptr,
                                                b_out, outf, MROWS);
}

// Round 9
// 449.391 us; speedup vs baseline: 1.1511x; 1.0174x over previous
//
#include <hip/hip_runtime.h>
#include <cstdint>
#include <cstddef>

#define DEVINL __device__ __forceinline__

typedef __attribute__((ext_vector_type(8))) short short8;
typedef __attribute__((ext_vector_type(4))) float f32x4;
typedef unsigned short u16;
typedef unsigned int u32;

// ---------- bf16 helpers (RNE) ----------
DEVINL u16 f2b(float f) {
    u32 u = __float_as_uint(f);
    u32 r = (u + 0x7fffu + ((u >> 16) & 1u)) >> 16;
    return (u16)r;
}
DEVINL float b2f(u16 h) { return __uint_as_float(((u32)h) << 16); }

DEVINL void gl_lds16(const void* g, void* l) {
    __builtin_amdgcn_global_load_lds(
        (const __attribute__((address_space(1))) void*)g,
        (__attribute__((address_space(3))) void*)l, 16, 0, 0);
}

// ---------- constants ----------
#define MROWS   25096
#define NTOK    3137
#define QE      25698304
#define LOG2E   1.4426950408889634f
#define SCL2    0.1803368801111204f   /* 0.125 * log2(e) */

// ---------- fp32 -> bf16 conversion ----------
__global__ __launch_bounds__(256) void cvt_kernel(const float* __restrict__ in,
                                                  u16* __restrict__ out, int n4) {
    int i = blockIdx.x * blockDim.x + threadIdx.x;
    int stride = gridDim.x * blockDim.x;
    for (int j = i; j < n4; j += stride) {
        float4 v = ((const float4*)in)[j];
        ushort4 o;
        o.x = f2b(v.x); o.y = f2b(v.y); o.z = f2b(v.z); o.w = f2b(v.w);
        ((ushort4*)out)[j] = o;
    }
}

// ================= 256x256 bf16 MFMA GEMM, read-ahead pipelined phases =================
// A row-major [M][1024], B = [N][1024] (B^T). K = 1024, NT = 16 K-tiles.
// 512 threads = 8 waves (2 M x 4 N). LDS: 2 bufs x (A[2][256][32]+B[2][256][32]) = 128 KiB.
// T2 slot swizzle as before (phys_slot = log ^ ((row>>1)&3); source pre-swizzled).
// Phase pipeline (1 barrier per phase; compiler emits counted lgkmcnt for read-ahead):
//  p1: read Ak0m0-3,Bk0,Ak0m4-7 ; stage A(nb,k0) ; MFMA(k0,m0-3) ; vmcnt(2)->cb k1 proven ; bar
//  p2: read Ak1m0-3,Bk1         ; stage B(nb,k0) ; MFMA(k0,m4-7)                          ; bar
//  p3: read Ak1m4-7             ; stage A(nb,k1) ; MFMA(k1,m0-3)                          ; bar
//  p4:                            stage B(nb,k1) ; MFMA(k1,m4-7) ; vmcnt(4)->nb k0 proven ; bar

#define LDS_BUF 32768
#define NTILES  16

template <int MODE>
__global__ __launch_bounds__(512, 2) void gemm256(const u16* __restrict__ A,
                                                  const u16* __restrict__ B,
                                                  u16* __restrict__ q_out,
                                                  u16* __restrict__ k_out,
                                                  u16* __restrict__ v_out,
                                                  const float* __restrict__ bias,
                                                  float* __restrict__ f_out, int M) {
    __shared__ u16 lds[2 * LDS_BUF];   // 128 KiB
    const int tid = threadIdx.x, lane = tid & 63, w = tid >> 6;
    const int Mm1 = M - 1;

    const u32 nwg = gridDim.x * gridDim.y;
    const u32 orig = blockIdx.y * gridDim.x + blockIdx.x;
    const u32 q8 = nwg >> 3, r8 = nwg & 7, xcd = orig & 7, rest = orig >> 3;
    const u32 wg = (xcd < r8 ? xcd * (q8 + 1) : r8 * (q8 + 1) + (xcd - r8) * q8) + rest;
    const int m0 = (int)(wg / gridDim.x) * 256;
    const int n0 = (int)(wg % gridDim.x) * 256;

    const int wm = w >> 2, wn = w & 3;

    const int stRow = lane >> 2;
    const int stCol = (((lane & 3) ^ ((lane >> 3) & 3)) << 3);

    const int slotOff = (((lane >> 4) ^ ((lane >> 1) & 3)) << 3);
    const int rdA = (wm * 128 + (lane & 15)) * 32 + slotOff;
    const int rdB = (wn * 64 + (lane & 15)) * 32 + slotOff + 16384;

#define STAGE_A(NB, KK, KT) do {                                              \
    _Pragma("unroll") for (int j_ = 0; j_ < 2; ++j_) {                        \
        const int c_ = (w << 1) | j_;                                         \
        int r_ = m0 + c_ * 16 + stRow; if (r_ > Mm1) r_ = Mm1;                \
        gl_lds16(A + (size_t)r_ * 1024 + (KT) + (KK) * 32 + stCol,            \
                 lds + (NB) + (KK) * 8192 + c_ * 512);                        \
    } } while (0)

#define STAGE_B(NB, KK, KT) do {                                              \
    _Pragma("unroll") for (int j_ = 0; j_ < 2; ++j_) {                        \
        const int c_ = (w << 1) | j_;                                         \
        const int r_ = n0 + c_ * 16 + stRow;                                  \
        gl_lds16(B + (size_t)r_ * 1024 + (KT) + (KK) * 32 + stCol,            \
                 lds + (NB) + 16384 + (KK) * 8192 + c_ * 512);                \
    } } while (0)

#define LDA4(DST, CB, KK, MB) do {                                            \
    _Pragma("unroll") for (int i_ = 0; i_ < 4; ++i_)                          \
        DST[i_] = *(const short8*)&lds[(CB) + (KK) * 8192 + rdA +             \
                                       ((MB) + i_) * 16 * 32];                \
    } while (0)

#define LDB4(DST, CB, KK) do {                                                \
    _Pragma("unroll") for (int i_ = 0; i_ < 4; ++i_)                          \
        DST[i_] = *(const short8*)&lds[(CB) + (KK) * 8192 + rdB +             \
                                       i_ * 16 * 32];                         \
    } while (0)

#define MFMA16(AV, BV, MB) do {                                               \
    _Pragma("unroll") for (int i_ = 0; i_ < 4; ++i_)                          \
        _Pragma("unroll") for (int n_ = 0; n_ < 4; ++n_)                      \
            acc[(MB) + i_][n_] = __builtin_amdgcn_mfma_f32_16x16x32_bf16(     \
                AV[i_], BV[n_], acc[(MB) + i_][n_], 0, 0, 0);                 \
    } while (0)

#define PHASE_BAR() do {                                                      \
    __builtin_amdgcn_s_barrier();                                             \
    __builtin_amdgcn_sched_barrier(0); } while (0)

    f32x4 acc[8][4];
    const f32x4 zf = {0.f, 0.f, 0.f, 0.f};
#pragma unroll
    for (int i = 0; i < 8; ++i)
#pragma unroll
        for (int j = 0; j < 4; ++j) acc[i][j] = zf;

    // ---- prologue: stage tile 0 fully into buf0, prove k0 halves ----
    STAGE_A(0, 0, 0);
    STAGE_B(0, 0, 0);
    STAGE_A(0, 1, 0);
    STAGE_B(0, 1, 0);
    asm volatile("s_waitcnt vmcnt(4)" ::: "memory");
    __builtin_amdgcn_sched_barrier(0);
    PHASE_BAR();

    for (int T = 0; T < NTILES; ++T) {
        const int cb = (T & 1) * LDS_BUF;
        const int nb = ((T + 1) & 1) * LDS_BUF;
        const bool pf = (T < NTILES - 1);
        const int kt1 = (T + 1) * 64;

        short8 a0m0[4], a0m4[4], a1m0[4], a1m4[4], b0[4], b1[4];

        // ---- phase 1: MFMA kk0 m0-3 ; read-ahead kk0 m4-7 ----
        LDA4(a0m0, cb, 0, 0);
        LDB4(b0,   cb, 0);
        LDA4(a0m4, cb, 0, 4);
        if (pf) STAGE_A(nb, 0, kt1);
        __builtin_amdgcn_s_setprio(1);
        MFMA16(a0m0, b0, 0);
        __builtin_amdgcn_s_setprio(0);
        if (pf) { asm volatile("s_waitcnt vmcnt(2)" ::: "memory"); }  // proves cb kk1
        else    { asm volatile("s_waitcnt vmcnt(0)" ::: "memory"); }
        __builtin_amdgcn_sched_barrier(0);
        PHASE_BAR();

        // ---- phase 2: MFMA kk0 m4-7 ; read-ahead kk1 m0-3 + Bk1 ----
        LDA4(a1m0, cb, 1, 0);
        LDB4(b1,   cb, 1);
        if (pf) STAGE_B(nb, 0, kt1);
        __builtin_amdgcn_s_setprio(1);
        MFMA16(a0m4, b0, 4);
        __builtin_amdgcn_s_setprio(0);
        PHASE_BAR();

        // ---- phase 3: MFMA kk1 m0-3 ; read-ahead kk1 m4-7 ----
        LDA4(a1m4, cb, 1, 4);
        if (pf) STAGE_A(nb, 1, kt1);
        __builtin_amdgcn_s_setprio(1);
        MFMA16(a1m0, b1, 0);
        __builtin_amdgcn_s_setprio(0);
        PHASE_BAR();

        // ---- phase 4: MFMA kk1 m4-7 ----
        if (pf) STAGE_B(nb, 1, kt1);
        __builtin_amdgcn_s_setprio(1);
        MFMA16(a1m4, b1, 4);
        __builtin_amdgcn_s_setprio(0);
        if (pf) {
            asm volatile("s_waitcnt vmcnt(4)" ::: "memory");  // proves nb kk0
            __builtin_amdgcn_sched_barrier(0);
        }
        PHASE_BAR();
    }

    // ---- epilogue: C layout col=lane&15, row=(lane>>4)*4+reg ----
#pragma unroll
    for (int m = 0; m < 8; ++m) {
#pragma unroll
        for (int n = 0; n < 4; ++n) {
#pragma unroll
            for (int r = 0; r < 4; ++r) {
                const int gm = m0 + wm * 128 + m * 16 + ((lane >> 4) << 2) + r;
                if (gm < M) {
                    const int gc = n0 + wn * 64 + n * 16 + (lane & 15);
                    if (MODE == 0) {
                        const int t = gc >> 10;
                        const int h = (gc >> 6) & 15;
                        const int d = gc & 63;
                        const u32 bb = (u32)gm / 3137u;
                        const u32 nn = (u32)gm - bb * 3137u;
                        u16* dst = (t == 0) ? q_out : (t == 1) ? k_out : v_out;
                        dst[(((size_t)(bb * 16 + h)) * NTOK + nn) * 64 + d] =
                            f2b(acc[m][n][r]);
                    } else {
                        f_out[(size_t)gm * 1024 + gc] = acc[m][n][r] + bias[gc];
                    }
                }
            }
        }
    }
#undef STAGE_A
#undef STAGE_B
#undef LDA4
#undef LDB4
#undef MFMA16
#undef PHASE_BAR
}

// ---------- cls attention, split-K flash ----------
#define CSZ 393
__global__ __launch_bounds__(256) void attn_cls_part(const u16* __restrict__ qb,
                                                     const u16* __restrict__ kb,
                                                     const u16* __restrict__ vb,
                                                     float* __restrict__ part) {
    const int bid = blockIdx.x;
    const int bh = bid >> 3, c = bid & 7;
    const size_t base = (size_t)bh * NTOK * 64;
    const int tid = threadIdx.x, lane = tid & 63, wid = tid >> 6;
    const int j0 = c * CSZ;
    const int cnt = min(NTOK - j0, CSZ);

    __shared__ float qs[64];
    __shared__ float sc[CSZ];
    __shared__ float redbuf[8];
    __shared__ float ored[4][64];

    if (tid < 64) qs[tid] = b2f(qb[base + tid]);
    __syncthreads();

    for (int j = tid; j < cnt; j += 256) {
        const u16* kr = kb + base + (size_t)(j0 + j) * 64;
        float acc = 0.f;
#pragma unroll
        for (int c2 = 0; c2 < 8; ++c2) {
            short8 v8 = *(const short8*)(kr + c2 * 8);
#pragma unroll
            for (int t = 0; t < 8; ++t) acc += qs[c2 * 8 + t] * b2f((u16)v8[t]);
        }
        sc[j] = acc * 0.125f;
    }
    __syncthreads();

    float mx = -1e30f;
    for (int j = tid; j < cnt; j += 256) mx = fmaxf(mx, sc[j]);
#pragma unroll
    for (int m = 32; m >= 1; m >>= 1) mx = fmaxf(mx, __shfl_xor(mx, m));
    if (lane == 0) redbuf[wid] = mx;
    __syncthreads();
    mx = fmaxf(fmaxf(redbuf[0], redbuf[1]), fmaxf(redbuf[2], redbuf[3]));

    float sum = 0.f;
    for (int j = tid; j < cnt; j += 256) {
        float p = exp2f((sc[j] - mx) * LOG2E);
        sc[j] = p;
        sum += p;
    }
#pragma unroll
    for (int m = 32; m >= 1; m >>= 1) sum += __shfl_xor(sum, m);
    if (lane == 0) redbuf[4 + wid] = sum;
    __syncthreads();
    const float tot = redbuf[4] + redbuf[5] + redbuf[6] + redbuf[7];

    const int d = tid & 63, g = tid >> 6;
    float o = 0.f;
    for (int j = g; j < cnt; j += 4)
        o += sc[j] * b2f(vb[base + (size_t)(j0 + j) * 64 + d]);
    ored[g][d] = o;
    __syncthreads();

    float* pb = part + (size_t)bid * 66;
    if (tid < 64) pb[2 + tid] = ored[0][tid] + ored[1][tid] + ored[2][tid] + ored[3][tid];
    else if (tid == 64) pb[0] = mx;
    else if (tid == 65) pb[1] = tot;
}

__global__ __launch_bounds__(64) void attn_cls_fin(const float* __restrict__ part,
                                                   u16* __restrict__ attnb) {
    const int bh = blockIdx.x, d = threadIdx.x;
    const int bb = bh >> 4, h = bh & 15;
    float m = -1e30f;
#pragma unroll
    for (int c = 0; c < 8; ++c) m = fmaxf(m, part[(size_t)(bh * 8 + c) * 66]);
    float t = 0.f, o = 0.f;
#pragma unroll
    for (int c = 0; c < 8; ++c) {
        const float* pb = part + (size_t)(bh * 8 + c) * 66;
        const float w = exp2f((pb[0] - m) * LOG2E);
        t += w * pb[1];
        o += w * pb[2 + d];
    }
    attnb[(size_t)bb * NTOK * 1024 + h * 64 + d] = f2b(o / t);
}

// ---------- spatial attention: swapped-QK, in-register P (round-7 version) ----------
__global__ __launch_bounds__(256, 3) void attn_spatial(const u16* __restrict__ qb,
                                                       const u16* __restrict__ kb,
                                                       const u16* __restrict__ vb,
                                                       u16* __restrict__ attnb) {
    const int blk = blockIdx.x;
    const int bh = blk >> 4, fi = blk & 15;
    const int bb = bh >> 4, h = bh & 15;
    const int tid = threadIdx.x, lane = tid & 63, wid = tid >> 6;
    const int hi = lane >> 4, lo = lane & 15;
    const size_t kvbase = (size_t)bh * NTOK * 64;

    __shared__ u16 Kl[208 * 64];   // XOR-swizzled K rows (197 real + 11 zero)
    __shared__ u16 Vt[64 * 208];   // V transposed, stride 208 (pad cols zero)

    const short8 z8 = {0, 0, 0, 0, 0, 0, 0, 0};

    for (int idx = tid; idx < 208 * 8; idx += 256) {
        const int j = idx >> 3, c = idx & 7;
        short8 kval = z8;
        if (j < 197) {
            const int n = (j == 0) ? 0 : (1 + fi * 196 + (j - 1));
            kval = *(const short8*)(kb + kvbase + (size_t)n * 64 + c * 8);
            const short8 v8 = *(const short8*)(vb + kvbase + (size_t)n * 64 + c * 8);
#pragma unroll
            for (int t0 = 0; t0 < 8; ++t0) {
                const int t = (t0 + c) & 7;
                Vt[(c * 8 + t) * 208 + j] = (u16)v8[t];
            }
        } else {
#pragma unroll
            for (int t = 0; t < 8; ++t) Vt[(c * 8 + t) * 208 + j] = 0;
        }
        *(short8*)(Kl + ((j * 64 + c * 8) ^ ((j & 7) << 3))) = kval;
    }
    __syncthreads();

    const int ksw = (lo & 7) << 3;
    const int src0 = lo + ((hi & 1) << 5);
    const int src1 = src0 + 16;
    const f32x4 zf = {0.f, 0.f, 0.f, 0.f};

    for (int mf = wid; mf < 13; mf += 4) {
        int qr = mf * 16 + lo; if (qr > 195) qr = 195;
        const u16* qp = qb + kvbase + (size_t)(1 + fi * 196 + qr) * 64 + hi * 8;
        const short8 qb0 = *(const short8*)(qp);
        const short8 qb1 = *(const short8*)(qp + 32);

        f32x4 s[13];
#pragma unroll
        for (int nf = 0; nf < 13; ++nf) s[nf] = zf;
#pragma unroll
        for (int nf = 0; nf < 13; ++nf) {
            const int e0 = (nf * 16 + lo) * 64 + hi * 8;
            const short8 a0 = *(const short8*)(Kl + (e0 ^ ksw));
            const short8 a1 = *(const short8*)(Kl + ((e0 + 32) ^ ksw));
            s[nf] = __builtin_amdgcn_mfma_f32_16x16x32_bf16(a0, qb0, s[nf], 0, 0, 0);
            s[nf] = __builtin_amdgcn_mfma_f32_16x16x32_bf16(a1, qb1, s[nf], 0, 0, 0);
        }

        float mx = s[0][0];
#pragma unroll
        for (int nf = 0; nf < 13; ++nf)
#pragma unroll
            for (int reg = 0; reg < 4; ++reg) mx = fmaxf(mx, s[nf][reg]);
        mx = fmaxf(mx, __shfl_xor(mx, 16));
        mx = fmaxf(mx, __shfl_xor(mx, 32));
        const float mC = mx * SCL2;
        float sum = 0.f;
#pragma unroll
        for (int nf = 0; nf < 13; ++nf)
#pragma unroll
            for (int reg = 0; reg < 4; ++reg) {
                const float p = exp2f(fmaf(s[nf][reg], SCL2, -mC));
                s[nf][reg] = p;
                sum += p;
            }
        sum += __shfl_xor(sum, 16);
        sum += __shfl_xor(sum, 32);
        const float rls = 1.0f / (sum - 11.0f * exp2f(-mC));

        u32 w0[13], w1[13];
#pragma unroll
        for (int nf = 0; nf < 13; ++nf) {
            const float p0 = s[nf][0] * rls, p1 = s[nf][1] * rls;
            const float p2 = s[nf][2] * rls, p3 = s[nf][3] * rls;
            asm("v_cvt_pk_bf16_f32 %0, %1, %2" : "=v"(w0[nf]) : "v"(p0), "v"(p1));
            asm("v_cvt_pk_bf16_f32 %0, %1, %2" : "=v"(w1[nf]) : "v"(p2), "v"(p3));
        }

        f32x4 o[4];
#pragma unroll
        for (int i = 0; i < 4; ++i) o[i] = zf;
#pragma unroll
        for (int kk = 0; kk < 7; ++kk) {
            u32 x0, x1, x2, x3;
            if (kk < 6) {
                const u32 aA0 = __shfl(w0[2 * kk], src0), aA1 = __shfl(w1[2 * kk], src0);
                const u32 aA2 = __shfl(w0[2 * kk], src1), aA3 = __shfl(w1[2 * kk], src1);
                const u32 aB0 = __shfl(w0[2 * kk + 1], src0), aB1 = __shfl(w1[2 * kk + 1], src0);
                const u32 aB2 = __shfl(w0[2 * kk + 1], src1), aB3 = __shfl(w1[2 * kk + 1], src1);
                const bool lh = hi < 2;
                x0 = lh ? aA0 : aB0; x1 = lh ? aA1 : aB1;
                x2 = lh ? aA2 : aB2; x3 = lh ? aA3 : aB3;
            } else {
                const u32 aA0 = __shfl(w0[12], src0), aA1 = __shfl(w1[12], src0);
                const u32 aA2 = __shfl(w0[12], src1), aA3 = __shfl(w1[12], src1);
                const bool lh = hi < 2;
                x0 = lh ? aA0 : 0u; x1 = lh ? aA1 : 0u;
                x2 = lh ? aA2 : 0u; x3 = lh ? aA3 : 0u;
            }
            union { u32 u[4]; short8 v; } pu;
            pu.u[0] = x0; pu.u[1] = x1; pu.u[2] = x2; pu.u[3] = x3;
            const short8 pa = pu.v;
#pragma unroll
            for (int nf2 = 0; nf2 < 4; ++nf2) {
                short8 bv = z8;
                if (kk < 6 || hi < 2)
                    bv = *(const short8*)(Vt + (nf2 * 16 + lo) * 208 + kk * 32 + hi * 8);
                o[nf2] = __builtin_amdgcn_mfma_f32_16x16x32_bf16(pa, bv, o[nf2], 0, 0, 0);
            }
        }

#pragma unroll
        for (int nf2 = 0; nf2 < 4; ++nf2)
#pragma unroll
            for (int reg = 0; reg < 4; ++reg) {
                const int r = mf * 16 + hi * 4 + reg;
                if (r < 196) {
                    const int d = nf2 * 16 + lo;
                    const size_t nn = 1 + fi * 196 + r;
                    attnb[((size_t)bb * NTOK + nn) * 1024 + h * 64 + d] =
                        f2b(o[nf2][reg]);
                }
            }
    }
}

// ---------- launch ----------
extern "C" void kernel_launch(void* const* d_in, const int* in_sizes, int n_in,
                              void* d_out, int out_size, void* d_ws, size_t ws_size,
                              hipStream_t stream) {
    const float* x = (const float*)d_in[0];
    const float* w_qkv = (const float*)d_in[1];
    const float* w_out = (const float*)d_in[2];
    const float* b_out = (const float*)d_in[3];

    const size_t need = ((size_t)QE * 2 + 3145728 + 1048576) * 2;
    if (ws_size < need) {
        hipMemsetAsync(d_out, 0, (size_t)out_size * 4, stream);
        return;
    }

    u16* vb = (u16*)d_ws;
    u16* xab = vb + QE;
    u16* wqb = xab + QE;
    u16* wob = wqb + 3145728;
    u16* qb = (u16*)d_out;
    u16* kb = qb + QE;
    float* outf = (float*)d_out;
    float* clsp = (float*)wqb;

    cvt_kernel<<<2048, 256, 0, stream>>>(x, xab, QE / 4);
    cvt_kernel<<<2048, 256, 0, stream>>>(w_qkv, wqb, 3145728 / 4);
    cvt_kernel<<<1024, 256, 0, stream>>>(w_out, wob, 1048576 / 4);

    gemm256<0><<<dim3(12, 99), 512, 0, stream>>>(xab, wqb, qb, kb, vb, nullptr,
                                                 nullptr, MROWS);
    attn_cls_part<<<1024, 256, 0, stream>>>(qb, kb, vb, clsp);
    attn_cls_fin<<<128, 64, 0, stream>>>(clsp, xab);
    attn_spatial<<<2048, 256, 0, stream>>>(qb, kb, vb, xab);
    gemm256<1><<<dim3(4, 99), 512, 0, stream>>>(xab, wob, nullptr, nullptr, nullptr,
                                                b_out, outf, MROWS);
}

// Round 11
// 447.597 us; speedup vs baseline: 1.1557x; 1.0040x over previous
//
#include <hip/hip_runtime.h>
#include <cstdint>
#include <cstddef>

#define DEVINL __device__ __forceinline__

typedef __attribute__((ext_vector_type(8))) short short8;
typedef __attribute__((ext_vector_type(4))) float f32x4;
typedef unsigned short u16;
typedef unsigned int u32;

// ---------- bf16 helpers (RNE) ----------
DEVINL u16 f2b(float f) {
    u32 u = __float_as_uint(f);
    u32 r = (u + 0x7fffu + ((u >> 16) & 1u)) >> 16;
    return (u16)r;
}
DEVINL float b2f(u16 h) { return __uint_as_float(((u32)h) << 16); }

DEVINL void gl_lds16(const void* g, void* l) {
    __builtin_amdgcn_global_load_lds(
        (const __attribute__((address_space(1))) void*)g,
        (__attribute__((address_space(3))) void*)l, 16, 0, 0);
}

// ---------- constants ----------
#define MROWS   25096
#define NTOK    3137
#define QE      25698304
#define LOG2E   1.4426950408889634f
#define SCL2    0.1803368801111204f   /* 0.125 * log2(e) */

// ---------- fp32 -> bf16 conversion ----------
__global__ __launch_bounds__(256) void cvt_kernel(const float* __restrict__ in,
                                                  u16* __restrict__ out, int n4) {
    int i = blockIdx.x * blockDim.x + threadIdx.x;
    int stride = gridDim.x * blockDim.x;
    for (int j = i; j < n4; j += stride) {
        float4 v = ((const float4*)in)[j];
        ushort4 o;
        o.x = f2b(v.x); o.y = f2b(v.y); o.z = f2b(v.z); o.w = f2b(v.w);
        ((ushort4*)out)[j] = o;
    }
}

// ================= 256x256 bf16 MFMA GEMM, fully-rotated read-ahead pipeline ===========
// A row-major [M][1024], B = [N][1024] (B^T). K = 1024, NT = 16 K-tiles.
// 512 threads = 8 waves (2M x 4N). LDS: 2 bufs x (A[2][256][32]+B[2][256][32]) = 128 KiB.
// T2 slot swizzle (phys_slot = log ^ ((row>>1)&3); source pre-swizzled).
// Every phase's MFMA operands are ds_read one phase earlier (p4 pre-reads next tile's p1
// frags from nb). vmcnt accounting (per-wave queue, 2 loads per STAGE):
//  p1: +STAGE_A(nb,k0) -> queue [cbA1,cbB1,nbA0]=6 ; vmcnt(2) completes cbA1+cbB1
//      -> cb kk1 proven for p2/p3 reads.
//  p3: +STAGE_A(nb,k1) -> queue [nbA0,nbB0,nbA1]=6 ; vmcnt(2) completes nbA0+nbB0
//      -> nb kk0 proven for p4 pre-read.
// Waits only touch loads issued 1-2 phases earlier; fresh loads never waited.

#define LDS_BUF 32768
#define NTILES  16

template <int MODE>
__global__ __launch_bounds__(512, 2) void gemm256(const u16* __restrict__ A,
                                                  const u16* __restrict__ B,
                                                  u16* __restrict__ q_out,
                                                  u16* __restrict__ k_out,
                                                  u16* __restrict__ v_out,
                                                  const float* __restrict__ bias,
                                                  float* __restrict__ f_out, int M) {
    __shared__ u16 lds[2 * LDS_BUF];   // 128 KiB
    const int tid = threadIdx.x, lane = tid & 63, w = tid >> 6;
    const int Mm1 = M - 1;

    const u32 nwg = gridDim.x * gridDim.y;
    const u32 orig = blockIdx.y * gridDim.x + blockIdx.x;
    const u32 q8 = nwg >> 3, r8 = nwg & 7, xcd = orig & 7, rest = orig >> 3;
    const u32 wg = (xcd < r8 ? xcd * (q8 + 1) : r8 * (q8 + 1) + (xcd - r8) * q8) + rest;
    const int m0 = (int)(wg / gridDim.x) * 256;
    const int n0 = (int)(wg % gridDim.x) * 256;

    const int wm = w >> 2, wn = w & 3;

    const int stRow = lane >> 2;
    const int stCol = (((lane & 3) ^ ((lane >> 3) & 3)) << 3);

    const int slotOff = (((lane >> 4) ^ ((lane >> 1) & 3)) << 3);
    const int rdA = (wm * 128 + (lane & 15)) * 32 + slotOff;
    const int rdB = (wn * 64 + (lane & 15)) * 32 + slotOff + 16384;

#define STAGE_A(NB, KK, KT) do {                                              \
    _Pragma("unroll") for (int j_ = 0; j_ < 2; ++j_) {                        \
        const int c_ = (w << 1) | j_;                                         \
        int r_ = m0 + c_ * 16 + stRow; if (r_ > Mm1) r_ = Mm1;                \
        gl_lds16(A + (size_t)r_ * 1024 + (KT) + (KK) * 32 + stCol,            \
                 lds + (NB) + (KK) * 8192 + c_ * 512);                        \
    } } while (0)

#define STAGE_B(NB, KK, KT) do {                                              \
    _Pragma("unroll") for (int j_ = 0; j_ < 2; ++j_) {                        \
        const int c_ = (w << 1) | j_;                                         \
        const int r_ = n0 + c_ * 16 + stRow;                                  \
        gl_lds16(B + (size_t)r_ * 1024 + (KT) + (KK) * 32 + stCol,            \
                 lds + (NB) + 16384 + (KK) * 8192 + c_ * 512);                \
    } } while (0)

#define LDA4(DST, CB, KK, MB) do {                                            \
    _Pragma("unroll") for (int i_ = 0; i_ < 4; ++i_)                          \
        DST[i_] = *(const short8*)&lds[(CB) + (KK) * 8192 + rdA +             \
                                       ((MB) + i_) * 16 * 32];                \
    } while (0)

#define LDB4(DST, CB, KK) do {                                                \
    _Pragma("unroll") for (int i_ = 0; i_ < 4; ++i_)                          \
        DST[i_] = *(const short8*)&lds[(CB) + (KK) * 8192 + rdB +             \
                                       i_ * 16 * 32];                         \
    } while (0)

#define MFMA16(AV, BV, MB) do {                                               \
    _Pragma("unroll") for (int i_ = 0; i_ < 4; ++i_)                          \
        _Pragma("unroll") for (int n_ = 0; n_ < 4; ++n_)                      \
            acc[(MB) + i_][n_] = __builtin_amdgcn_mfma_f32_16x16x32_bf16(     \
                AV[i_], BV[n_], acc[(MB) + i_][n_], 0, 0, 0);                 \
    } while (0)

#define VMW(N) do {                                                           \
    asm volatile("s_waitcnt vmcnt(" #N ")" ::: "memory");                     \
    __builtin_amdgcn_sched_barrier(0); } while (0)

#define PHASE_BAR() do {                                                      \
    __builtin_amdgcn_s_barrier();                                             \
    __builtin_amdgcn_sched_barrier(0); } while (0)

    f32x4 acc[8][4];
    const f32x4 zf = {0.f, 0.f, 0.f, 0.f};
#pragma unroll
    for (int i = 0; i < 8; ++i)
#pragma unroll
        for (int j = 0; j < 4; ++j) acc[i][j] = zf;

    // ---- prologue: stage tile 0 into buf0; prove kk0; pre-read T=0 p1 frags ----
    STAGE_A(0, 0, 0);
    STAGE_B(0, 0, 0);
    STAGE_A(0, 1, 0);
    STAGE_B(0, 1, 0);
    VMW(4);            // completes kk0 A+B; kk1 A+B (4) outstanding
    PHASE_BAR();

    short8 ra[4], rb[4];
    LDA4(ra, 0, 0, 0);
    LDB4(rb, 0, 0);

    for (int T = 0; T < NTILES; ++T) {
        const int cb = (T & 1) * LDS_BUF;
        const int nb = ((T + 1) & 1) * LDS_BUF;
        const bool pf = (T < NTILES - 1);
        const int kt1 = (T + 1) * 64;

        short8 a4[4], c0[4], d0[4], e4[4];

        // ---- phase 1: MFMA kk0 m0-3 (ra,rb) ; read-ahead kk0 m4-7 ----
        LDA4(a4, cb, 0, 4);
        if (pf) STAGE_A(nb, 0, kt1);
        __builtin_amdgcn_s_setprio(1);
        MFMA16(ra, rb, 0);
        __builtin_amdgcn_s_setprio(0);
        if (pf) { VMW(2); }   // completes cb kk1 A+B (staged prev p3+p4)
        else    { VMW(0); }
        PHASE_BAR();

        // ---- phase 2: MFMA kk0 m4-7 ; read-ahead kk1 m0-3 + Bk1 ----
        LDA4(c0, cb, 1, 0);
        LDB4(d0, cb, 1);
        if (pf) STAGE_B(nb, 0, kt1);
        __builtin_amdgcn_s_setprio(1);
        MFMA16(a4, rb, 4);
        __builtin_amdgcn_s_setprio(0);
        PHASE_BAR();

        // ---- phase 3: MFMA kk1 m0-3 ; read-ahead kk1 m4-7 ----
        LDA4(e4, cb, 1, 4);
        if (pf) STAGE_A(nb, 1, kt1);
        __builtin_amdgcn_s_setprio(1);
        MFMA16(c0, d0, 0);
        __builtin_amdgcn_s_setprio(0);
        if (pf) { VMW(2); }   // completes nb kk0 A+B (staged this p1+p2)
        PHASE_BAR();

        // ---- phase 4: MFMA kk1 m4-7 ; pre-read next tile's p1 frags from nb ----
        if (pf) {
            LDA4(ra, nb, 0, 0);
            LDB4(rb, nb, 0);
            STAGE_B(nb, 1, kt1);
        }
        __builtin_amdgcn_s_setprio(1);
        MFMA16(e4, d0, 4);
        __builtin_amdgcn_s_setprio(0);
        PHASE_BAR();
    }

    // ---- epilogue: C layout col=lane&15, row=(lane>>4)*4+reg ----
#pragma unroll
    for (int m = 0; m < 8; ++m) {
#pragma unroll
        for (int n = 0; n < 4; ++n) {
#pragma unroll
            for (int r = 0; r < 4; ++r) {
                const int gm = m0 + wm * 128 + m * 16 + ((lane >> 4) << 2) + r;
                if (gm < M) {
                    const int gc = n0 + wn * 64 + n * 16 + (lane & 15);
                    if (MODE == 0) {
                        const int t = gc >> 10;
                        const int h = (gc >> 6) & 15;
                        const int d = gc & 63;
                        const u32 bb = (u32)gm / 3137u;
                        const u32 nn = (u32)gm - bb * 3137u;
                        u16* dst = (t == 0) ? q_out : (t == 1) ? k_out : v_out;
                        dst[(((size_t)(bb * 16 + h)) * NTOK + nn) * 64 + d] =
                            f2b(acc[m][n][r]);
                    } else {
                        f_out[(size_t)gm * 1024 + gc] = acc[m][n][r] + bias[gc];
                    }
                }
            }
        }
    }
#undef STAGE_A
#undef STAGE_B
#undef LDA4
#undef LDB4
#undef MFMA16
#undef VMW
#undef PHASE_BAR
}

// ---------- cls attention, split-K flash ----------
#define CSZ 393
__global__ __launch_bounds__(256) void attn_cls_part(const u16* __restrict__ qb,
                                                     const u16* __restrict__ kb,
                                                     const u16* __restrict__ vb,
                                                     float* __restrict__ part) {
    const int bid = blockIdx.x;
    const int bh = bid >> 3, c = bid & 7;
    const size_t base = (size_t)bh * NTOK * 64;
    const int tid = threadIdx.x, lane = tid & 63, wid = tid >> 6;
    const int j0 = c * CSZ;
    const int cnt = min(NTOK - j0, CSZ);

    __shared__ float qs[64];
    __shared__ float sc[CSZ];
    __shared__ float redbuf[8];
    __shared__ float ored[4][64];

    if (tid < 64) qs[tid] = b2f(qb[base + tid]);
    __syncthreads();

    for (int j = tid; j < cnt; j += 256) {
        const u16* kr = kb + base + (size_t)(j0 + j) * 64;
        float acc = 0.f;
#pragma unroll
        for (int c2 = 0; c2 < 8; ++c2) {
            short8 v8 = *(const short8*)(kr + c2 * 8);
#pragma unroll
            for (int t = 0; t < 8; ++t) acc += qs[c2 * 8 + t] * b2f((u16)v8[t]);
        }
        sc[j] = acc * 0.125f;
    }
    __syncthreads();

    float mx = -1e30f;
    for (int j = tid; j < cnt; j += 256) mx = fmaxf(mx, sc[j]);
#pragma unroll
    for (int m = 32; m >= 1; m >>= 1) mx = fmaxf(mx, __shfl_xor(mx, m));
    if (lane == 0) redbuf[wid] = mx;
    __syncthreads();
    mx = fmaxf(fmaxf(redbuf[0], redbuf[1]), fmaxf(redbuf[2], redbuf[3]));

    float sum = 0.f;
    for (int j = tid; j < cnt; j += 256) {
        float p = exp2f((sc[j] - mx) * LOG2E);
        sc[j] = p;
        sum += p;
    }
#pragma unroll
    for (int m = 32; m >= 1; m >>= 1) sum += __shfl_xor(sum, m);
    if (lane == 0) redbuf[4 + wid] = sum;
    __syncthreads();
    const float tot = redbuf[4] + redbuf[5] + redbuf[6] + redbuf[7];

    const int d = tid & 63, g = tid >> 6;
    float o = 0.f;
    for (int j = g; j < cnt; j += 4)
        o += sc[j] * b2f(vb[base + (size_t)(j0 + j) * 64 + d]);
    ored[g][d] = o;
    __syncthreads();

    float* pb = part + (size_t)bid * 66;
    if (tid < 64) pb[2 + tid] = ored[0][tid] + ored[1][tid] + ored[2][tid] + ored[3][tid];
    else if (tid == 64) pb[0] = mx;
    else if (tid == 65) pb[1] = tot;
}

__global__ __launch_bounds__(64) void attn_cls_fin(const float* __restrict__ part,
                                                   u16* __restrict__ attnb) {
    const int bh = blockIdx.x, d = threadIdx.x;
    const int bb = bh >> 4, h = bh & 15;
    float m = -1e30f;
#pragma unroll
    for (int c = 0; c < 8; ++c) m = fmaxf(m, part[(size_t)(bh * 8 + c) * 66]);
    float t = 0.f, o = 0.f;
#pragma unroll
    for (int c = 0; c < 8; ++c) {
        const float* pb = part + (size_t)(bh * 8 + c) * 66;
        const float w = exp2f((pb[0] - m) * LOG2E);
        t += w * pb[1];
        o += w * pb[2 + d];
    }
    attnb[(size_t)bb * NTOK * 1024 + h * 64 + d] = f2b(o / t);
}

// ---------- spatial attention: swapped-QK, in-register unnormalized P ----------
__global__ __launch_bounds__(256, 3) void attn_spatial(const u16* __restrict__ qb,
                                                       const u16* __restrict__ kb,
                                                       const u16* __restrict__ vb,
                                                       u16* __restrict__ attnb) {
    const int blk = blockIdx.x;
    const int bh = blk >> 4, fi = blk & 15;
    const int bb = bh >> 4, h = bh & 15;
    const int tid = threadIdx.x, lane = tid & 63, wid = tid >> 6;
    const int hi = lane >> 4, lo = lane & 15;
    const size_t kvbase = (size_t)bh * NTOK * 64;

    __shared__ u16 Kl[208 * 64];   // XOR-swizzled K rows (197 real + 11 zero)
    __shared__ u16 Vt[64 * 208];   // V transposed, stride 208 (pad cols zero)

    const short8 z8 = {0, 0, 0, 0, 0, 0, 0, 0};

    for (int idx = tid; idx < 208 * 8; idx += 256) {
        const int j = idx >> 3, c = idx & 7;
        short8 kval = z8;
        if (j < 197) {
            const int n = (j == 0) ? 0 : (1 + fi * 196 + (j - 1));
            kval = *(const short8*)(kb + kvbase + (size_t)n * 64 + c * 8);
            const short8 v8 = *(const short8*)(vb + kvbase + (size_t)n * 64 + c * 8);
#pragma unroll
            for (int t0 = 0; t0 < 8; ++t0) {
                const int t = (t0 + c) & 7;
                Vt[(c * 8 + t) * 208 + j] = (u16)v8[t];
            }
        } else {
#pragma unroll
            for (int t = 0; t < 8; ++t) Vt[(c * 8 + t) * 208 + j] = 0;
        }
        *(short8*)(Kl + ((j * 64 + c * 8) ^ ((j & 7) << 3))) = kval;
    }
    __syncthreads();

    const int ksw = (lo & 7) << 3;
    const int src0 = lo + ((hi & 1) << 5);
    const int src1 = src0 + 16;
    const f32x4 zf = {0.f, 0.f, 0.f, 0.f};

    for (int mf = wid; mf < 13; mf += 4) {
        int qr = mf * 16 + lo; if (qr > 195) qr = 195;
        const u16* qp = qb + kvbase + (size_t)(1 + fi * 196 + qr) * 64 + hi * 8;
        const short8 qb0 = *(const short8*)(qp);
        const short8 qb1 = *(const short8*)(qp + 32);

        f32x4 s[13];
#pragma unroll
        for (int nf = 0; nf < 13; ++nf) s[nf] = zf;
#pragma unroll
        for (int nf = 0; nf < 13; ++nf) {
            const int e0 = (nf * 16 + lo) * 64 + hi * 8;
            const short8 a0 = *(const short8*)(Kl + (e0 ^ ksw));
            const short8 a1 = *(const short8*)(Kl + ((e0 + 32) ^ ksw));
            s[nf] = __builtin_amdgcn_mfma_f32_16x16x32_bf16(a0, qb0, s[nf], 0, 0, 0);
            s[nf] = __builtin_amdgcn_mfma_f32_16x16x32_bf16(a1, qb1, s[nf], 0, 0, 0);
        }

        float mx = s[0][0];
#pragma unroll
        for (int nf = 0; nf < 13; ++nf)
#pragma unroll
            for (int reg = 0; reg < 4; ++reg) mx = fmaxf(mx, s[nf][reg]);
        mx = fmaxf(mx, __shfl_xor(mx, 16));
        mx = fmaxf(mx, __shfl_xor(mx, 32));
        const float mC = mx * SCL2;
        float sum = 0.f;
#pragma unroll
        for (int nf = 0; nf < 13; ++nf)
#pragma unroll
            for (int reg = 0; reg < 4; ++reg) {
                const float p = exp2f(fmaf(s[nf][reg], SCL2, -mC));
                s[nf][reg] = p;
                sum += p;
            }
        sum += __shfl_xor(sum, 16);
        sum += __shfl_xor(sum, 32);
        const float rls = 1.0f / (sum - 11.0f * exp2f(-mC));

        // pack UNNORMALIZED P (values in [0,1])
        u32 w0[13], w1[13];
#pragma unroll
        for (int nf = 0; nf < 13; ++nf) {
            asm("v_cvt_pk_bf16_f32 %0, %1, %2"
                : "=v"(w0[nf]) : "v"(s[nf][0]), "v"(s[nf][1]));
            asm("v_cvt_pk_bf16_f32 %0, %1, %2"
                : "=v"(w1[nf]) : "v"(s[nf][2]), "v"(s[nf][3]));
        }

        f32x4 o[4];
#pragma unroll
        for (int i = 0; i < 4; ++i) o[i] = zf;
#pragma unroll
        for (int kk = 0; kk < 7; ++kk) {
            u32 x0, x1, x2, x3;
            if (kk < 6) {
                const u32 aA0 = __shfl(w0[2 * kk], src0), aA1 = __shfl(w1[2 * kk], src0);
                const u32 aA2 = __shfl(w0[2 * kk], src1), aA3 = __shfl(w1[2 * kk], src1);
                const u32 aB0 = __shfl(w0[2 * kk + 1], src0), aB1 = __shfl(w1[2 * kk + 1], src0);
                const u32 aB2 = __shfl(w0[2 * kk + 1], src1), aB3 = __shfl(w1[2 * kk + 1], src1);
                const bool lh = hi < 2;
                x0 = lh ? aA0 : aB0; x1 = lh ? aA1 : aB1;
                x2 = lh ? aA2 : aB2; x3 = lh ? aA3 : aB3;
            } else {
                const u32 aA0 = __shfl(w0[12], src0), aA1 = __shfl(w1[12], src0);
                const u32 aA2 = __shfl(w0[12], src1), aA3 = __shfl(w1[12], src1);
                const bool lh = hi < 2;
                x0 = lh ? aA0 : 0u; x1 = lh ? aA1 : 0u;
                x2 = lh ? aA2 : 0u; x3 = lh ? aA3 : 0u;
            }
            union { u32 u[4]; short8 v; } pu;
            pu.u[0] = x0; pu.u[1] = x1; pu.u[2] = x2; pu.u[3] = x3;
            const short8 pa = pu.v;
#pragma unroll
            for (int nf2 = 0; nf2 < 4; ++nf2) {
                short8 bv = z8;
                if (kk < 6 || hi < 2)
                    bv = *(const short8*)(Vt + (nf2 * 16 + lo) * 208 + kk * 32 + hi * 8);
                o[nf2] = __builtin_amdgcn_mfma_f32_16x16x32_bf16(pa, bv, o[nf2], 0, 0, 0);
            }
        }

        // epilogue: O row q = mf*16 + 4hi + reg needs rls of q' = 4hi+reg (lane q' holds it)
        float rr[4];
#pragma unroll
        for (int reg = 0; reg < 4; ++reg) rr[reg] = __shfl(rls, hi * 4 + reg);
#pragma unroll
        for (int nf2 = 0; nf2 < 4; ++nf2)
#pragma unroll
            for (int reg = 0; reg < 4; ++reg) {
                const int r = mf * 16 + hi * 4 + reg;
                if (r < 196) {
                    const int d = nf2 * 16 + lo;
                    const size_t nn = 1 + fi * 196 + r;
                    attnb[((size_t)bb * NTOK + nn) * 1024 + h * 64 + d] =
                        f2b(o[nf2][reg] * rr[reg]);
                }
            }
    }
}

// ---------- launch ----------
extern "C" void kernel_launch(void* const* d_in, const int* in_sizes, int n_in,
                              void* d_out, int out_size, void* d_ws, size_t ws_size,
                              hipStream_t stream) {
    const float* x = (const float*)d_in[0];
    const float* w_qkv = (const float*)d_in[1];
    const float* w_out = (const float*)d_in[2];
    const float* b_out = (const float*)d_in[3];

    const size_t need = ((size_t)QE * 2 + 3145728 + 1048576) * 2;
    if (ws_size < need) {
        hipMemsetAsync(d_out, 0, (size_t)out_size * 4, stream);
        return;
    }

    u16* vb = (u16*)d_ws;
    u16* xab = vb + QE;
    u16* wqb = xab + QE;
    u16* wob = wqb + 3145728;
    u16* qb = (u16*)d_out;
    u16* kb = qb + QE;
    float* outf = (float*)d_out;
    float* clsp = (float*)wqb;

    cvt_kernel<<<2048, 256, 0, stream>>>(x, xab, QE / 4);
    cvt_kernel<<<2048, 256, 0, stream>>>(w_qkv, wqb, 3145728 / 4);
    cvt_kernel<<<1024, 256, 0, stream>>>(w_out, wob, 1048576 / 4);

    gemm256<0><<<dim3(12, 99), 512, 0, stream>>>(xab, wqb, qb, kb, vb, nullptr,
                                                 nullptr, MROWS);
    attn_cls_part<<<1024, 256, 0, stream>>>(qb, kb, vb, clsp);
    attn_cls_fin<<<128, 64, 0, stream>>>(clsp, xab);
    attn_spatial<<<2048, 256, 0, stream>>>(qb, kb, vb, xab);
    gemm256<1><<<dim3(4, 99), 512, 0, stream>>>(xab, wob, nullptr, nullptr, nullptr,
                                                b_out, outf, MROWS);
}